// Round 3
// baseline (175.868 us; speedup 1.0000x reference)
//
#include <hip/hip_runtime.h>

// SWA non-overlapping window MHA, MI355X gfx950.
// B=8, S=4096, D=512, W=128, H=8, hd=64 -> 256 windows, M=32768 tokens.
// K1 convert fp32->bf16 (x, w_in, w_out)
// K2 QKV GEMM  [32768x1536x512] pipelined 256x256xBK32 -> qk (d_out scratch) + vT (ws)
// K3 attention per (window, head), no barriers -> ctx bf16 [M][512]
// K4 out-proj GEMM [32768x512x512] + bias -> fp32 d_out (same pipelined template)

typedef __bf16 bf16x8 __attribute__((ext_vector_type(8)));
typedef __bf16 bf16x4 __attribute__((ext_vector_type(4)));
typedef float  f32x4  __attribute__((ext_vector_type(4)));

#define MFMA16(a, b, c) __builtin_amdgcn_mfma_f32_16x16x32_bf16((a), (b), (c), 0, 0, 0)

#define VMCNT(n) asm volatile("s_waitcnt vmcnt(" #n ")" ::: "memory")
#define SBAR() do { __builtin_amdgcn_sched_barrier(0); \
                    __builtin_amdgcn_s_barrier(); \
                    __builtin_amdgcn_sched_barrier(0); } while (0)

__device__ __forceinline__ void gload_lds16(const __bf16* g, void* l) {
    __builtin_amdgcn_global_load_lds(
        (const __attribute__((address_space(1))) unsigned int*)g,
        (__attribute__((address_space(3))) unsigned int*)l, 16, 0, 0);
}

// ---------------- K1: fp32 -> bf16 conversion ----------------
__device__ __forceinline__ void cvt8(const float* __restrict__ s,
                                     __bf16* __restrict__ d, long i) {
    const float4* s4 = reinterpret_cast<const float4*>(s);
    float4 a = s4[2 * i], b = s4[2 * i + 1];
    bf16x8 v;
    v[0] = (__bf16)a.x; v[1] = (__bf16)a.y; v[2] = (__bf16)a.z; v[3] = (__bf16)a.w;
    v[4] = (__bf16)b.x; v[5] = (__bf16)b.y; v[6] = (__bf16)b.z; v[7] = (__bf16)b.w;
    *reinterpret_cast<bf16x8*>(d + 8 * i) = v;
}

__global__ void convert_k(const float* __restrict__ x,
                          const float* __restrict__ w_in,
                          const float* __restrict__ w_out,
                          __bf16* __restrict__ x_bf,
                          __bf16* __restrict__ w_in_bf,
                          __bf16* __restrict__ w_out_bf)
{
    long i0 = (long)blockIdx.x * blockDim.x + threadIdx.x;
    long stride = (long)gridDim.x * blockDim.x;
    for (long i = i0; i < 16777216 / 8; i += stride) cvt8(x, x_bf, i);
    for (long i = i0; i < 786432 / 8;   i += stride) cvt8(w_in, w_in_bf, i);
    for (long i = i0; i < 262144 / 8;   i += stride) cvt8(w_out, w_out_bf, i);
}

// ---------------- K2/K4: pipelined 256x256 GEMM, BK=32, K=512 (16 tiles) ----------------
// 4-deep LDS ring per operand (4 x 16 KB), counted vmcnt (never 0 in steady state),
// raw s_barrier (no waitcnt drain), 8 waves (wave tile 128x64).
// A [M][512] bf16 rm, Bw [N][512] bf16 rm. EPI 0: qkv epilogue. EPI 1: fp32 + bias.
template<int EPI, int NN>
__global__ __launch_bounds__(512, 2)
void gemm256(const __bf16* __restrict__ A,
             const __bf16* __restrict__ Bw,
             const float* __restrict__ bias,
             void* __restrict__ Cq,
             __bf16* __restrict__ vT)
{
    // [slot][256 rows][32 k] bf16 = 16 KB per slot; 4 slots per operand = 128 KiB total
    __shared__ __bf16 Al[4][8192];
    __shared__ __bf16 Bl[4][8192];

    const int nwg = gridDim.x;
    const int chunk = nwg >> 3;                       // nwg % 8 == 0
    const int bid = blockIdx.x;
    const int wg = (bid & 7) * chunk + (bid >> 3);    // XCD-contiguous chunks
    const int nidx = wg % NN;
    const int midx = wg / NN;
    const long mbase = (long)midx * 256;
    const int colbase = nidx * 256;

    const int tid = threadIdx.x;
    const int w = tid >> 6, lane = tid & 63;
    const int lrow = lane & 15, hi = lane >> 4;
    const int wm = w >> 2, wn = w & 3;                // wave tile: rows 128*wm, cols 64*wn

    // staging thread coords: 64 lanes cover 16 rows x 4 slots of 16B (one 1-KB wave chunk)
    const int st_row = lane >> 2;                     // 0..15
    const int st_slot = lane & 3;
    const int st_k = 8 * (st_slot ^ ((lane >> 3) & 3));   // pre-swizzled global k-offset
    // read-side swizzle: slot = hi ^ ((lrow>>1)&3)  (involution with the above)
    const int rd_off = 16 * (hi ^ ((lrow >> 1) & 3));

    const __bf16* PA = A  + (mbase + w * 16 + st_row) * 512 + st_k;
    const __bf16* PB = Bw + ((long)colbase + w * 16 + st_row) * 512 + st_k;
    const int lds_w = w * 1024;                       // per-wave chunk within 8-KB half

    f32x4 acc[8][4];
    #pragma unroll
    for (int rt = 0; rt < 8; ++rt)
        #pragma unroll
        for (int ct = 0; ct < 4; ++ct) acc[rt][ct] = (f32x4){0.f, 0.f, 0.f, 0.f};

    // ---- stage issue for K-tile tt ----
    auto stage = [&](int tt) {
        const int sl = tt & 3;
        const int kk = tt * 32;
        char* As = (char*)Al[sl];
        char* Bs = (char*)Bl[sl];
        gload_lds16(PA + kk,             As + lds_w);            // A rows 0..127
        gload_lds16(PA + 128 * 512 + kk, As + 8192 + lds_w);     // A rows 128..255
        gload_lds16(PB + kk,             Bs + lds_w);
        gload_lds16(PB + 128 * 512 + kk, Bs + 8192 + lds_w);
    };

    // ---- compute body for K-tile t ----
    auto body = [&](int t) {
        const char* As = (const char*)Al[t & 3];
        const char* Bs = (const char*)Bl[t & 3];
        bf16x8 af[8], bf[4];
        #pragma unroll
        for (int rt = 0; rt < 8; ++rt) {
            int row = 128 * wm + 16 * rt + lrow;
            af[rt] = *reinterpret_cast<const bf16x8*>(As + row * 64 + rd_off);
        }
        #pragma unroll
        for (int ct = 0; ct < 4; ++ct) {
            int row = 64 * wn + 16 * ct + lrow;
            bf[ct] = *reinterpret_cast<const bf16x8*>(Bs + row * 64 + rd_off);
        }
        __builtin_amdgcn_s_setprio(1);
        #pragma unroll
        for (int rt = 0; rt < 8; ++rt)
            #pragma unroll
            for (int ct = 0; ct < 4; ++ct)
                acc[rt][ct] = MFMA16(af[rt], bf[ct], acc[rt][ct]);
        __builtin_amdgcn_s_setprio(0);
    };

    // prologue: stage tiles 0,1,2 (12 loads/thread); wait until K0 landed (8 left)
    stage(0); stage(1); stage(2);
    VMCNT(8);
    SBAR();

    // steady state: stage t+3, compute t, leave 8 loads (2 tiles) in flight
    #pragma unroll 1
    for (int t = 0; t < 13; ++t) {
        stage(t + 3);
        body(t);
        VMCNT(8);
        SBAR();
    }
    body(13); VMCNT(4); SBAR();
    body(14); VMCNT(0); SBAR();
    body(15);

    // ---- epilogue ----
    if (EPI == 0) {
        const int region = colbase >> 9;              // 0=q, 1=k, 2=v
        if (region < 2) {
            __bf16* qk = (__bf16*)Cq;                 // [M][1024]
            const float scale = (region == 0) ? 0.125f : 1.0f;
            #pragma unroll
            for (int ct = 0; ct < 4; ++ct) {
                int colg = colbase + 64 * wn + 16 * ct + lrow;
                float b = bias[colg];
                #pragma unroll
                for (int rt = 0; rt < 8; ++rt) {
                    long row = mbase + 128 * wm + 16 * rt + 4 * hi;
                    #pragma unroll
                    for (int r = 0; r < 4; ++r)
                        qk[(row + r) * 1024 + colg] = (__bf16)((acc[rt][ct][r] + b) * scale);
                }
            }
        } else {
            // v: store transposed vT[win][h][d][tok], 4 consecutive toks packed
            #pragma unroll
            for (int ct = 0; ct < 4; ++ct) {
                int colg = colbase + 64 * wn + 16 * ct + lrow;
                float b = bias[colg];
                int e2 = colg - 1024;
                int h = e2 >> 6, d = e2 & 63;
                #pragma unroll
                for (int rt = 0; rt < 8; ++rt) {
                    long row = mbase + 128 * wm + 16 * rt + 4 * hi;
                    int win = (int)(row >> 7), tok0 = (int)(row & 127);
                    bf16x4 pk;
                    pk[0] = (__bf16)(acc[rt][ct][0] + b);
                    pk[1] = (__bf16)(acc[rt][ct][1] + b);
                    pk[2] = (__bf16)(acc[rt][ct][2] + b);
                    pk[3] = (__bf16)(acc[rt][ct][3] + b);
                    *reinterpret_cast<bf16x4*>(
                        vT + (((long)win * 8 + h) * 64 + d) * 128 + tok0) = pk;
                }
            }
        }
    } else {
        float* out = (float*)Cq;                      // [M][512] fp32
        #pragma unroll
        for (int ct = 0; ct < 4; ++ct) {
            int colg = colbase + 64 * wn + 16 * ct + lrow;
            float b = bias[colg];
            #pragma unroll
            for (int rt = 0; rt < 8; ++rt) {
                long row = mbase + 128 * wm + 16 * rt + 4 * hi;
                #pragma unroll
                for (int r = 0; r < 4; ++r)
                    out[(row + r) * 512 + colg] = acc[rt][ct][r] + b;
            }
        }
    }
}

// ---------------- K3: attention per (window, head), no barriers ----------------
// grid = 2048 (win*8 + h), block = 256 (4 waves; wave w owns q rows 32w..32w+31)
__global__ __launch_bounds__(256)
void swa_attn(const __bf16* __restrict__ qk,   // [32768][1024]  q cols 0-511 (scaled), k cols 512-1023
              const __bf16* __restrict__ vT,   // [256][8][64][128]
              __bf16* __restrict__ ctx)        // [32768][512]
{
    __shared__ __bf16 p_lds[4][32][136];

    const int bid = blockIdx.x;
    const int win = bid >> 3, h = bid & 7;
    const int tid = threadIdx.x;
    const int w = tid >> 6, lane = tid & 63;
    const int lrow = lane & 15, hi = lane >> 4;
    const long tokb = (long)win * 128;

    // q a-frags for this wave's 32 rows (2 row-frags x 2 k-slices)
    bf16x8 qa[2][2];
    #pragma unroll
    for (int rt = 0; rt < 2; ++rt)
        #pragma unroll
        for (int ks = 0; ks < 2; ++ks)
            qa[rt][ks] = *reinterpret_cast<const bf16x8*>(
                qk + (tokb + 32 * w + 16 * rt + lrow) * 1024 + h * 64 + ks * 32 + hi * 8);

    // scores s[2][8]: 32 q-rows x 128 k-tokens
    f32x4 s[2][8];
    #pragma unroll
    for (int rt = 0; rt < 2; ++rt)
        #pragma unroll
        for (int ct = 0; ct < 8; ++ct) s[rt][ct] = (f32x4){0.f, 0.f, 0.f, 0.f};
    #pragma unroll
    for (int ks = 0; ks < 2; ++ks) {
        #pragma unroll
        for (int ct = 0; ct < 8; ++ct) {
            bf16x8 kb = *reinterpret_cast<const bf16x8*>(
                qk + (tokb + 16 * ct + lrow) * 1024 + 512 + h * 64 + ks * 32 + hi * 8);
            s[0][ct] = MFMA16(qa[0][ks], kb, s[0][ct]);
            s[1][ct] = MFMA16(qa[1][ks], kb, s[1][ct]);
        }
    }

    // softmax per row (row = 16rt + 4hi + r, cols spread over lrow x ct)
    float inv[2][4];
    #pragma unroll
    for (int rt = 0; rt < 2; ++rt) {
        #pragma unroll
        for (int r = 0; r < 4; ++r) {
            float m = s[rt][0][r];
            #pragma unroll
            for (int ct = 1; ct < 8; ++ct) m = fmaxf(m, s[rt][ct][r]);
            m = fmaxf(m, __shfl_xor(m, 1));
            m = fmaxf(m, __shfl_xor(m, 2));
            m = fmaxf(m, __shfl_xor(m, 4));
            m = fmaxf(m, __shfl_xor(m, 8));
            float sum = 0.f;
            #pragma unroll
            for (int ct = 0; ct < 8; ++ct) {
                float e = __expf(s[rt][ct][r] - m);
                sum += e;
                p_lds[w][16 * rt + 4 * hi + r][16 * ct + lrow] = (__bf16)e;
            }
            sum += __shfl_xor(sum, 1);
            sum += __shfl_xor(sum, 2);
            sum += __shfl_xor(sum, 4);
            sum += __shfl_xor(sum, 8);
            inv[rt][r] = 1.f / sum;
        }
    }
    // no barrier: p_lds[w] is wave-private; compiler orders same-wave LDS RAW

    // PV: o[2][4] = P @ V  (b-frag from vT: contiguous tok reads)
    f32x4 o[2][4];
    #pragma unroll
    for (int rt = 0; rt < 2; ++rt)
        #pragma unroll
        for (int ct = 0; ct < 4; ++ct) o[rt][ct] = (f32x4){0.f, 0.f, 0.f, 0.f};
    const __bf16* vb = vT + ((long)win * 8 + h) * 64 * 128;
    #pragma unroll
    for (int kt = 0; kt < 4; ++kt) {
        bf16x8 pa0 = *reinterpret_cast<const bf16x8*>(&p_lds[w][lrow][32 * kt + 8 * hi]);
        bf16x8 pa1 = *reinterpret_cast<const bf16x8*>(&p_lds[w][16 + lrow][32 * kt + 8 * hi]);
        #pragma unroll
        for (int ct = 0; ct < 4; ++ct) {
            bf16x8 vf = *reinterpret_cast<const bf16x8*>(
                vb + (16 * ct + lrow) * 128 + 32 * kt + 8 * hi);
            o[0][ct] = MFMA16(pa0, vf, o[0][ct]);
            o[1][ct] = MFMA16(pa1, vf, o[1][ct]);
        }
    }

    #pragma unroll
    for (int rt = 0; rt < 2; ++rt)
        #pragma unroll
        for (int ct = 0; ct < 4; ++ct)
            #pragma unroll
            for (int r = 0; r < 4; ++r) {
                long tok = tokb + 32 * w + 16 * rt + 4 * hi + r;
                ctx[tok * 512 + h * 64 + 16 * ct + lrow] =
                    (__bf16)(o[rt][ct][r] * inv[rt][r]);
            }
}

extern "C" void kernel_launch(void* const* d_in, const int* in_sizes, int n_in,
                              void* d_out, int out_size, void* d_ws, size_t ws_size,
                              hipStream_t stream)
{
    const float* x     = (const float*)d_in[0];
    const float* w_in  = (const float*)d_in[1];
    const float* b_in  = (const float*)d_in[2];
    const float* w_out = (const float*)d_in[3];
    const float* b_out = (const float*)d_in[4];

    // ws layout (bytes): [x_bf -> later ctx: 0, 33554432) [vT: 33554432, 67108864)
    //                    [w_in_bf: 67108864, +1572864) [w_out_bf: 68681728, +524288)
    // total 69,206,016 B. qk scratch (67.1 MB bf16) lives in d_out until K4.
    char* ws = (char*)d_ws;
    __bf16* x_bf     = (__bf16*)(ws);
    __bf16* ctx      = (__bf16*)(ws);                  // reuses x_bf after K2
    __bf16* vT       = (__bf16*)(ws + 33554432);
    __bf16* w_in_bf  = (__bf16*)(ws + 67108864);
    __bf16* w_out_bf = (__bf16*)(ws + 68681728);
    __bf16* qk       = (__bf16*)d_out;

    convert_k<<<2048, 256, 0, stream>>>(x, w_in, w_out, x_bf, w_in_bf, w_out_bf);
    gemm256<0, 6><<<768, 512, 0, stream>>>(x_bf, w_in_bf, b_in, (void*)qk, vT);
    swa_attn<<<2048, 256, 0, stream>>>(qk, vT, ctx);
    gemm256<1, 2><<<256, 512, 0, stream>>>(ctx, w_out_bf, b_out, d_out, nullptr);
}

// Round 4
// 167.880 us; speedup vs baseline: 1.0476x; 1.0476x over previous
//
#include <hip/hip_runtime.h>

// SWA non-overlapping window MHA, MI355X gfx950.
// B=8, S=4096, D=512, W=128, H=8, hd=64 -> 256 windows, M=32768 tokens.
// K1 convert fp32->bf16 (x, w_in, w_out)
// K2 QKV GEMM  [32768x1536x512] 8-phase-style pipelined 256x256xBK32 -> qk + vT
// K3 attention per (window, head), no barriers -> ctx bf16 [M][512]
// K4 out-proj GEMM [32768x512x512] + bias -> fp32 d_out (same template)

typedef __bf16 bf16x8 __attribute__((ext_vector_type(8)));
typedef __bf16 bf16x4 __attribute__((ext_vector_type(4)));
typedef float  f32x4  __attribute__((ext_vector_type(4)));

#define MFMA16(a, b, c) __builtin_amdgcn_mfma_f32_16x16x32_bf16((a), (b), (c), 0, 0, 0)

#define VMCNT_(n) asm volatile("s_waitcnt vmcnt(" #n ")" ::: "memory")
#define VMCNT(n) VMCNT_(n)
#define SBAR() do { __builtin_amdgcn_sched_barrier(0); \
                    __builtin_amdgcn_s_barrier(); \
                    __builtin_amdgcn_sched_barrier(0); } while (0)

__device__ __forceinline__ void gload_lds16(const __bf16* g, void* l) {
    __builtin_amdgcn_global_load_lds(
        (const __attribute__((address_space(1))) unsigned int*)g,
        (__attribute__((address_space(3))) unsigned int*)l, 16, 0, 0);
}

// ---------------- K1: fp32 -> bf16 conversion ----------------
__device__ __forceinline__ void cvt8(const float* __restrict__ s,
                                     __bf16* __restrict__ d, long i) {
    const float4* s4 = reinterpret_cast<const float4*>(s);
    float4 a = s4[2 * i], b = s4[2 * i + 1];
    bf16x8 v;
    v[0] = (__bf16)a.x; v[1] = (__bf16)a.y; v[2] = (__bf16)a.z; v[3] = (__bf16)a.w;
    v[4] = (__bf16)b.x; v[5] = (__bf16)b.y; v[6] = (__bf16)b.z; v[7] = (__bf16)b.w;
    *reinterpret_cast<bf16x8*>(d + 8 * i) = v;
}

__global__ void convert_k(const float* __restrict__ x,
                          const float* __restrict__ w_in,
                          const float* __restrict__ w_out,
                          __bf16* __restrict__ x_bf,
                          __bf16* __restrict__ w_in_bf,
                          __bf16* __restrict__ w_out_bf)
{
    long i0 = (long)blockIdx.x * blockDim.x + threadIdx.x;
    long stride = (long)gridDim.x * blockDim.x;
    for (long i = i0; i < 16777216 / 8; i += stride) cvt8(x, x_bf, i);
    for (long i = i0; i < 786432 / 8;   i += stride) cvt8(w_in, w_in_bf, i);
    for (long i = i0; i < 262144 / 8;   i += stride) cvt8(w_out, w_out_bf, i);
}

// ---------------- K2/K4: fine-phase pipelined 256x256 GEMM, BK=32, K=512 ----------------
// 4-deep LDS ring per operand, counted vmcnt (never 0 until drain ladder),
// two fine phases per K-tile: {ds_read subtile || 2 global_load_lds -> bar ->
// setprio+16 MFMA -> bar}, vmcnt(8) once per K-tile before the final barrier.
template<int EPI, int NN>
__global__ __launch_bounds__(512, 2)
void gemm256(const __bf16* __restrict__ A,
             const __bf16* __restrict__ Bw,
             const float* __restrict__ bias,
             void* __restrict__ Cq,
             __bf16* __restrict__ vT)
{
    // [slot][256 rows][32 k] bf16 = 16 KB per slot; 4 slots per operand = 128 KiB
    __shared__ __bf16 Al[4][8192];
    __shared__ __bf16 Bl[4][8192];

    const int nwg = gridDim.x;
    const int chunk = nwg >> 3;                       // nwg % 8 == 0
    const int bid = blockIdx.x;
    const int wg = (bid & 7) * chunk + (bid >> 3);    // XCD-contiguous chunks
    const int nidx = wg % NN;
    const int midx = wg / NN;
    const long mbase = (long)midx * 256;
    const int colbase = nidx * 256;

    const int tid = threadIdx.x;
    const int w = tid >> 6, lane = tid & 63;
    const int lrow = lane & 15, hi = lane >> 4;
    const int wm = w >> 2, wn = w & 3;                // wave tile: rows 128*wm, cols 64*wn

    // staging coords: 64 lanes cover 16 rows x 4 k-slots of 16B (1-KB wave chunk)
    const int st_row = lane >> 2;
    const int st_k = 8 * ((lane & 3) ^ ((lane >> 3) & 3));   // pre-swizzled k-slot
    // read-side swizzle (involution with the above): slot = hi ^ ((lrow>>1)&3)
    const int rd_off = 16 * (hi ^ ((lrow >> 1) & 3));

    const __bf16* PA = A  + (mbase + w * 16 + st_row) * 512 + st_k;
    const __bf16* PB = Bw + ((long)colbase + w * 16 + st_row) * 512 + st_k;
    const int lds_w = w * 1024;

    f32x4 acc[8][4];
    #pragma unroll
    for (int rt = 0; rt < 8; ++rt)
        #pragma unroll
        for (int ct = 0; ct < 4; ++ct) acc[rt][ct] = (f32x4){0.f, 0.f, 0.f, 0.f};

    auto stageA = [&](int tt) {   // A rows 0..127 and 128..255 of tile tt
        char* As = (char*)Al[tt & 3];
        gload_lds16(PA + tt * 32,             As + lds_w);
        gload_lds16(PA + 128 * 512 + tt * 32, As + 8192 + lds_w);
    };
    auto stageB = [&](int tt) {
        char* Bs = (char*)Bl[tt & 3];
        gload_lds16(PB + tt * 32,             Bs + lds_w);
        gload_lds16(PB + 128 * 512 + tt * 32, Bs + 8192 + lds_w);
    };

    // One K-tile = two fine phases. DO_STG: stage tile T+3. VMC: vmcnt before last bar.
    bf16x8 af[4], bfr[4];
#define TILE_BODY(T, DO_STG, DO_VM, VMC)                                          \
    {                                                                             \
        const char* As = (const char*)Al[(T) & 3];                                \
        const char* Bs = (const char*)Bl[(T) & 3];                                \
        /* ---- phase A: wave-tile rows 0-63, all 4 col-frags ---- */             \
        _Pragma("unroll")                                                         \
        for (int rt = 0; rt < 4; ++rt) {                                          \
            int row = 128 * wm + 16 * rt + lrow;                                  \
            af[rt] = *reinterpret_cast<const bf16x8*>(As + row * 64 + rd_off);    \
        }                                                                         \
        _Pragma("unroll")                                                         \
        for (int ct = 0; ct < 4; ++ct) {                                          \
            int row = 64 * wn + 16 * ct + lrow;                                   \
            bfr[ct] = *reinterpret_cast<const bf16x8*>(Bs + row * 64 + rd_off);   \
        }                                                                         \
        if (DO_STG) stageA((T) + 3);                                              \
        SBAR();                                                                   \
        __builtin_amdgcn_s_setprio(1);                                            \
        _Pragma("unroll")                                                         \
        for (int rt = 0; rt < 4; ++rt)                                            \
            _Pragma("unroll")                                                     \
            for (int ct = 0; ct < 4; ++ct)                                        \
                acc[rt][ct] = MFMA16(af[rt], bfr[ct], acc[rt][ct]);               \
        __builtin_amdgcn_s_setprio(0);                                            \
        SBAR();                                                                   \
        /* ---- phase B: wave-tile rows 64-127, reuse bfr ---- */                 \
        _Pragma("unroll")                                                         \
        for (int rt = 0; rt < 4; ++rt) {                                          \
            int row = 128 * wm + 64 + 16 * rt + lrow;                             \
            af[rt] = *reinterpret_cast<const bf16x8*>(As + row * 64 + rd_off);    \
        }                                                                         \
        if (DO_STG) stageB((T) + 3);                                              \
        SBAR();                                                                   \
        __builtin_amdgcn_s_setprio(1);                                            \
        _Pragma("unroll")                                                         \
        for (int rt = 0; rt < 4; ++rt)                                            \
            _Pragma("unroll")                                                     \
            for (int ct = 0; ct < 4; ++ct)                                        \
                acc[4 + rt][ct] = MFMA16(af[rt], bfr[ct], acc[4 + rt][ct]);       \
        __builtin_amdgcn_s_setprio(0);                                            \
        if (DO_VM) { VMCNT(VMC); }                                                \
        SBAR();                                                                   \
    }

    // prologue: stage tiles 0,1,2 (12 loads/thread); wait until tile 0 landed
    stageA(0); stageB(0); stageA(1); stageB(1); stageA(2); stageB(2);
    VMCNT(8);
    SBAR();

    #pragma unroll 1
    for (int t = 0; t < 13; ++t) TILE_BODY(t, 1, 1, 8);
    TILE_BODY(13, 0, 1, 4);
    TILE_BODY(14, 0, 1, 0);
    TILE_BODY(15, 0, 0, 0);
#undef TILE_BODY

    // ---- epilogue ----
    if (EPI == 0) {
        const int region = colbase >> 9;              // 0=q, 1=k, 2=v
        if (region < 2) {
            __bf16* qk = (__bf16*)Cq;                 // [M][1024]
            const float scale = (region == 0) ? 0.125f : 1.0f;
            #pragma unroll
            for (int ct = 0; ct < 4; ++ct) {
                int colg = colbase + 64 * wn + 16 * ct + lrow;
                float b = bias[colg];
                #pragma unroll
                for (int rt = 0; rt < 8; ++rt) {
                    long row = mbase + 128 * wm + 16 * rt + 4 * hi;
                    #pragma unroll
                    for (int r = 0; r < 4; ++r)
                        qk[(row + r) * 1024 + colg] = (__bf16)((acc[rt][ct][r] + b) * scale);
                }
            }
        } else {
            // v: store transposed vT[win][h][d][tok], 4 consecutive toks packed
            #pragma unroll
            for (int ct = 0; ct < 4; ++ct) {
                int colg = colbase + 64 * wn + 16 * ct + lrow;
                float b = bias[colg];
                int e2 = colg - 1024;
                int h = e2 >> 6, d = e2 & 63;
                #pragma unroll
                for (int rt = 0; rt < 8; ++rt) {
                    long row = mbase + 128 * wm + 16 * rt + 4 * hi;
                    int win = (int)(row >> 7), tok0 = (int)(row & 127);
                    bf16x4 pk;
                    pk[0] = (__bf16)(acc[rt][ct][0] + b);
                    pk[1] = (__bf16)(acc[rt][ct][1] + b);
                    pk[2] = (__bf16)(acc[rt][ct][2] + b);
                    pk[3] = (__bf16)(acc[rt][ct][3] + b);
                    *reinterpret_cast<bf16x4*>(
                        vT + (((long)win * 8 + h) * 64 + d) * 128 + tok0) = pk;
                }
            }
        }
    } else {
        float* out = (float*)Cq;                      // [M][512] fp32
        #pragma unroll
        for (int ct = 0; ct < 4; ++ct) {
            int colg = colbase + 64 * wn + 16 * ct + lrow;
            float b = bias[colg];
            #pragma unroll
            for (int rt = 0; rt < 8; ++rt) {
                long row = mbase + 128 * wm + 16 * rt + 4 * hi;
                #pragma unroll
                for (int r = 0; r < 4; ++r)
                    out[(row + r) * 512 + colg] = acc[rt][ct][r] + b;
            }
        }
    }
}

// ---------------- K3: attention per (window, head), no barriers ----------------
// grid = 2048 (win*8 + h), block = 256 (4 waves; wave w owns q rows 32w..32w+31)
__global__ __launch_bounds__(256)
void swa_attn(const __bf16* __restrict__ qk,   // [32768][1024]  q cols 0-511 (scaled), k cols 512-1023
              const __bf16* __restrict__ vT,   // [256][8][64][128]
              __bf16* __restrict__ ctx)        // [32768][512]
{
    __shared__ __bf16 p_lds[4][32][136];

    const int bid = blockIdx.x;
    const int win = bid >> 3, h = bid & 7;
    const int tid = threadIdx.x;
    const int w = tid >> 6, lane = tid & 63;
    const int lrow = lane & 15, hi = lane >> 4;
    const long tokb = (long)win * 128;

    // q a-frags for this wave's 32 rows (2 row-frags x 2 k-slices)
    bf16x8 qa[2][2];
    #pragma unroll
    for (int rt = 0; rt < 2; ++rt)
        #pragma unroll
        for (int ks = 0; ks < 2; ++ks)
            qa[rt][ks] = *reinterpret_cast<const bf16x8*>(
                qk + (tokb + 32 * w + 16 * rt + lrow) * 1024 + h * 64 + ks * 32 + hi * 8);

    // scores s[2][8]: 32 q-rows x 128 k-tokens
    f32x4 s[2][8];
    #pragma unroll
    for (int rt = 0; rt < 2; ++rt)
        #pragma unroll
        for (int ct = 0; ct < 8; ++ct) s[rt][ct] = (f32x4){0.f, 0.f, 0.f, 0.f};
    #pragma unroll
    for (int ks = 0; ks < 2; ++ks) {
        #pragma unroll
        for (int ct = 0; ct < 8; ++ct) {
            bf16x8 kb = *reinterpret_cast<const bf16x8*>(
                qk + (tokb + 16 * ct + lrow) * 1024 + 512 + h * 64 + ks * 32 + hi * 8);
            s[0][ct] = MFMA16(qa[0][ks], kb, s[0][ct]);
            s[1][ct] = MFMA16(qa[1][ks], kb, s[1][ct]);
        }
    }

    // softmax per row (row = 16rt + 4hi + r, cols spread over lrow x ct)
    float inv[2][4];
    #pragma unroll
    for (int rt = 0; rt < 2; ++rt) {
        #pragma unroll
        for (int r = 0; r < 4; ++r) {
            float m = s[rt][0][r];
            #pragma unroll
            for (int ct = 1; ct < 8; ++ct) m = fmaxf(m, s[rt][ct][r]);
            m = fmaxf(m, __shfl_xor(m, 1));
            m = fmaxf(m, __shfl_xor(m, 2));
            m = fmaxf(m, __shfl_xor(m, 4));
            m = fmaxf(m, __shfl_xor(m, 8));
            float sum = 0.f;
            #pragma unroll
            for (int ct = 0; ct < 8; ++ct) {
                float e = __expf(s[rt][ct][r] - m);
                sum += e;
                p_lds[w][16 * rt + 4 * hi + r][16 * ct + lrow] = (__bf16)e;
            }
            sum += __shfl_xor(sum, 1);
            sum += __shfl_xor(sum, 2);
            sum += __shfl_xor(sum, 4);
            sum += __shfl_xor(sum, 8);
            inv[rt][r] = 1.f / sum;
        }
    }
    // no barrier: p_lds[w] is wave-private; compiler orders same-wave LDS RAW

    // PV: o[2][4] = P @ V  (b-frag from vT: contiguous tok reads)
    f32x4 o[2][4];
    #pragma unroll
    for (int rt = 0; rt < 2; ++rt)
        #pragma unroll
        for (int ct = 0; ct < 4; ++ct) o[rt][ct] = (f32x4){0.f, 0.f, 0.f, 0.f};
    const __bf16* vb = vT + ((long)win * 8 + h) * 64 * 128;
    #pragma unroll
    for (int kt = 0; kt < 4; ++kt) {
        bf16x8 pa0 = *reinterpret_cast<const bf16x8*>(&p_lds[w][lrow][32 * kt + 8 * hi]);
        bf16x8 pa1 = *reinterpret_cast<const bf16x8*>(&p_lds[w][16 + lrow][32 * kt + 8 * hi]);
        #pragma unroll
        for (int ct = 0; ct < 4; ++ct) {
            bf16x8 vf = *reinterpret_cast<const bf16x8*>(
                vb + (16 * ct + lrow) * 128 + 32 * kt + 8 * hi);
            o[0][ct] = MFMA16(pa0, vf, o[0][ct]);
            o[1][ct] = MFMA16(pa1, vf, o[1][ct]);
        }
    }

    #pragma unroll
    for (int rt = 0; rt < 2; ++rt)
        #pragma unroll
        for (int ct = 0; ct < 4; ++ct)
            #pragma unroll
            for (int r = 0; r < 4; ++r) {
                long tok = tokb + 32 * w + 16 * rt + 4 * hi + r;
                ctx[tok * 512 + h * 64 + 16 * ct + lrow] =
                    (__bf16)(o[rt][ct][r] * inv[rt][r]);
            }
}

extern "C" void kernel_launch(void* const* d_in, const int* in_sizes, int n_in,
                              void* d_out, int out_size, void* d_ws, size_t ws_size,
                              hipStream_t stream)
{
    const float* x     = (const float*)d_in[0];
    const float* w_in  = (const float*)d_in[1];
    const float* b_in  = (const float*)d_in[2];
    const float* w_out = (const float*)d_in[3];
    const float* b_out = (const float*)d_in[4];

    // ws layout (bytes): [x_bf -> later ctx: 0, 33554432) [vT: 33554432, 67108864)
    //                    [w_in_bf: 67108864, +1572864) [w_out_bf: 68681728, +524288)
    // total 69,206,016 B. qk scratch (67.1 MB bf16) lives in d_out until K4.
    char* ws = (char*)d_ws;
    __bf16* x_bf     = (__bf16*)(ws);
    __bf16* ctx      = (__bf16*)(ws);                  // reuses x_bf after K2
    __bf16* vT       = (__bf16*)(ws + 33554432);
    __bf16* w_in_bf  = (__bf16*)(ws + 67108864);
    __bf16* w_out_bf = (__bf16*)(ws + 68681728);
    __bf16* qk       = (__bf16*)d_out;

    convert_k<<<2048, 256, 0, stream>>>(x, w_in, w_out, x_bf, w_in_bf, w_out_bf);
    gemm256<0, 6><<<768, 512, 0, stream>>>(x_bf, w_in_bf, b_in, (void*)qk, vT);
    swa_attn<<<2048, 256, 0, stream>>>(qk, vT, ctx);
    gemm256<1, 2><<<256, 512, 0, stream>>>(ctx, w_out_bf, b_out, d_out, nullptr);
}